// Round 9
// baseline (324.959 us; speedup 1.0000x reference)
//
#include <hip/hip_runtime.h>
#include <math.h>

// Problem constants (fixed by the reference)
#define BB   2
#define SS   2304
#define DINC 1024
#define DIMC 1024
#define HH   16
#define HD   64

typedef _Float16 half_t;
typedef __attribute__((ext_vector_type(4))) _Float16 half4;   // 2 VGPRs
typedef __attribute__((ext_vector_type(8))) _Float16 half8;   // 4 VGPRs
typedef __attribute__((ext_vector_type(4))) float    f32x4;   // 4 VGPRs

#define LOG2E 1.44269504088896340736f
#define EXP2(x) __builtin_amdgcn_exp2f(x)     // raw v_exp_f32, no libm guard path

// async global->LDS, 16B per lane; LDS dest = wave-uniform base + lane*16
#define GLOAD_LDS16(gp, lp)                                                     \
    __builtin_amdgcn_global_load_lds(                                           \
        (const __attribute__((address_space(1))) void*)(gp),                    \
        (__attribute__((address_space(3))) void*)(lp), 16, 0, 0)

// ---------------------------------------------------------------------------
// Converter: fp32 row-major [R][K] -> f16 tile-blocked [R/RB][K/32][RB][32].
// ---------------------------------------------------------------------------
template<int RB>
__global__ __launch_bounds__(256)
void convert_tile_f16(const float* __restrict__ src, half_t* __restrict__ dst, int K)
{
    constexpr int EPT = RB * 32 / 256;       // elements per thread (16 or 8)
    const int mb = blockIdx.x;
    const int kb = blockIdx.y;
    const int t  = threadIdx.x;
    const int e0 = t * EPT;
    const int mm = e0 >> 5;
    const int kk = e0 & 31;
    const float* sp = src + (size_t)(mb * RB + mm) * K + kb * 32 + kk;
    half_t*      dp = dst + ((size_t)mb * (K >> 5) + kb) * (RB * 32) + mm * 32 + kk;
    #pragma unroll
    for (int g = 0; g < EPT / 4; ++g) {
        float4 v = *(const float4*)(sp + 4 * g);
        dp[4 * g + 0] = (half_t)v.x; dp[4 * g + 1] = (half_t)v.y;
        dp[4 * g + 2] = (half_t)v.z; dp[4 * g + 3] = (half_t)v.w;
    }
}

// ---------------------------------------------------------------------------
// f16 MFMA GEMM (NT): C[m][n] = sum_k A[m][k]*W[n][k] + bias[n], fp32 accum.
// (unchanged from round 8)
// ---------------------------------------------------------------------------
template<int BN, bool OUT_HALF>
__global__ __launch_bounds__(256)
void gemm_mfma(const half_t* __restrict__ Ah, const half_t* __restrict__ Bh,
               const float* __restrict__ bias, void* __restrict__ Cout,
               int M, int N, int K)
{
    constexpr int MT = (BN == 128) ? 4 : 2;
    constexpr int NT = 4;
    const int KB = K >> 5;
    __shared__ half_t As[8192];          // [u][128][32]
    __shared__ half_t Bs[2 * BN * 32];   // [u][BN][32]

    const int t    = threadIdx.x;
    const int w    = t >> 6;
    const int lane = t & 63;
    const int l15  = lane & 15, quad = lane >> 4;
    const int wr   = (BN == 128) ? (w >> 1) : w;
    const int wc   = (BN == 128) ? (w & 1) : 0;
    const int mb   = blockIdx.y, nb = blockIdx.x;

    f32x4 acc[MT][NT];
    #pragma unroll
    for (int mt = 0; mt < MT; ++mt)
        #pragma unroll
        for (int nt = 0; nt < NT; ++nt) acc[mt][nt] = (f32x4){0.f, 0.f, 0.f, 0.f};

    const half_t* atile = Ah + (size_t)mb * KB * 4096;
    const half_t* btile = Bh + (size_t)nb * KB * (BN * 32);

    for (int kb = 0; kb < KB; kb += 2) {
        #pragma unroll
        for (int u = 0; u < 2; ++u) {
            const half_t* at = atile + (size_t)(kb + u) * 4096;
            const half_t* bt = btile + (size_t)(kb + u) * (BN * 32);
            #pragma unroll
            for (int v = 0; v < 2; ++v) {
                const int ch = w * 2 + v;
                GLOAD_LDS16(at + ch * 512 + lane * 8, As + u * 4096 + ch * 512);
            }
            if (BN == 128) {
                #pragma unroll
                for (int v = 0; v < 2; ++v) {
                    const int ch = w * 2 + v;
                    GLOAD_LDS16(bt + ch * 512 + lane * 8, Bs + u * 4096 + ch * 512);
                }
            } else {
                GLOAD_LDS16(bt + w * 512 + lane * 8, Bs + u * (BN * 32) + w * 512);
            }
        }
        __syncthreads();

        #pragma unroll
        for (int u = 0; u < 2; ++u) {
            half8 af[MT], bf[NT];
            #pragma unroll
            for (int mt = 0; mt < MT; ++mt)
                af[mt] = *(const half8*)(As + u * 4096
                                         + (wr * (MT * 16) + mt * 16 + l15) * 32 + quad * 8);
            #pragma unroll
            for (int nt = 0; nt < NT; ++nt)
                bf[nt] = *(const half8*)(Bs + u * (BN * 32)
                                         + (wc * 64 + nt * 16 + l15) * 32 + quad * 8);
            #pragma unroll
            for (int mt = 0; mt < MT; ++mt)
                #pragma unroll
                for (int nt = 0; nt < NT; ++nt)
                    acc[mt][nt] = __builtin_amdgcn_mfma_f32_16x16x32_f16(
                        af[mt], bf[nt], acc[mt][nt], 0, 0, 0);
        }
        __syncthreads();
    }

    const int bm = mb * 128, bn = nb * BN;
    #pragma unroll
    for (int nt = 0; nt < NT; ++nt) {
        const int n  = bn + wc * 64 + nt * 16 + l15;
        const float bv = bias[n];
        #pragma unroll
        for (int mt = 0; mt < MT; ++mt) {
            const int m0 = bm + wr * (MT * 16) + mt * 16 + quad * 4;
            #pragma unroll
            for (int rg = 0; rg < 4; ++rg) {
                const float v = acc[mt][nt][rg] + bv;
                if (OUT_HALF) ((half_t*)Cout)[(size_t)(m0 + rg) * N + n] = (half_t)v;
                else          ((float*) Cout)[(size_t)(m0 + rg) * N + n] = v;
            }
        }
    }
}

// ---------------------------------------------------------------------------
// RMSNorm + axial 2D RoPE, 512 threads: group sel=t>>8 handles q (0) / k (1)
// in PARALLEL (halves critical path vs sequential v6). fp32 math.
// Token group = 64 tokens; wave slice jt=(s>>4)&1; within-slice k-index
// k' = ((s>>5)&1)*16 + (s&15)  (0..31).
//  - Q (scaled 0.125*log2e, rotated) -> in place (halfs [0,1024))
//  - K -> Kf: [bh][g36][jt][ktile(2)][dt2(2)][lane64][8] with the PV-fusing
//    permutation: ktile=(k'>>2)&1, row m=((k'>>3)<<2)+(k'&3), lane=m+16*kq
//    (kq=(d&31)>>3) -> QK^T C-tile rows concatenate into K=32 PV B-operand.
//  - V -> Vf: [bh][g36][jt][dt(4)][lane64][8], lane=(d&15)+16*(k'>>3),
//    i=k'&7  (A-operand of the K=32 PV MFMA).
// ---------------------------------------------------------------------------
__global__ __launch_bounds__(512)
void normrope_v7(half_t* __restrict__ qkvh, const float* __restrict__ q_scale,
                 const float* __restrict__ k_scale, const int* __restrict__ wptr,
                 half_t* __restrict__ Kf, half_t* __restrict__ Vf)
{
    const int token = blockIdx.x;        // b*SS + s
    const int s     = token % SS;
    const int b     = token / SS;
    const int w     = *wptr;
    const int t     = threadIdx.x;
    const float rowp = (float)(s / w);
    const float colp = (float)(s % w);

    half_t* base = qkvh + (size_t)token * 3072;

    const int g36 = s >> 6;              // 64-token group
    const int jt  = (s >> 4) & 1;
    const int kp_ = ((s >> 5) & 1) * 16 + (s & 15);   // k' 0..31

    // ---- V -> Vf (2 elements per thread across 512 threads) ----
    {
        const int e0 = 2 * t;
        const int kq = kp_ >> 3, ki = kp_ & 7;
        #pragma unroll
        for (int ii = 0; ii < 2; ++ii) {
            const int e = e0 + ii;
            const int h = e >> 6;
            const int d = e & 63;
            half_t* vdst = Vf + (((size_t)(b * HH + h) * 36 + g36) * 2 + jt) * 2048;
            vdst[(size_t)(d >> 4) * 512 + ((d & 15) + 16 * kq) * 8 + ki] = base[2048 + e];
        }
    }

    __shared__ float buf[2][DIMC];
    __shared__ float red[8];

    const int sel = t >> 8;              // 0: q, 1: k
    const int tl  = t & 255;
    half_t* row = base + sel * DIMC;
    const float* scp = sel ? k_scale : q_scale;

    half4 xh = *(const half4*)(row + 4 * tl);
    float x0 = (float)xh[0], x1 = (float)xh[1], x2 = (float)xh[2], x3 = (float)xh[3];
    float ss = x0 * x0 + x1 * x1 + x2 * x2 + x3 * x3;
    #pragma unroll
    for (int o = 32; o >= 1; o >>= 1) ss += __shfl_xor(ss, o);
    if ((tl & 63) == 0) red[sel * 4 + (tl >> 6)] = ss;
    __syncthreads();

    const float rinv = rsqrtf((red[sel * 4 + 0] + red[sel * 4 + 1]
                             + red[sel * 4 + 2] + red[sel * 4 + 3]) * (1.0f / DIMC) + 1e-6f);
    float4 g = *(const float4*)(scp + 4 * tl);
    buf[sel][4 * tl + 0] = x0 * rinv * g.x;
    buf[sel][4 * tl + 1] = x1 * rinv * g.y;
    buf[sel][4 * tl + 2] = x2 * rinv * g.z;
    buf[sel][4 * tl + 3] = x3 * rinv * g.w;
    __syncthreads();

    const float qsc = sel ? 1.0f : (0.125f * LOG2E);  // log2-domain scores
    const int ktile = (kp_ >> 2) & 1;
    const int km    = ((kp_ >> 3) << 2) + (kp_ & 3);

    #pragma unroll
    for (int pp = 0; pp < 2; ++pp) {
        const int p = tl + pp * 256;
        const int h = p >> 5;
        const int r = p & 31;
        const int j = r & 15;
        const float pos = (r < 16) ? rowp : colp;
        const int d1 = (r < 16) ? j : (32 + j);   // within-head dim
        const int d2 = d1 + 16;
        const float freq = exp2f((float)j * -0.83048202372f);
        const float ang  = pos * freq;
        float sn, cs;
        __sincosf(ang, &sn, &cs);
        const float a1 = buf[sel][h * HD + d1], a2 = buf[sel][h * HD + d2];
        const float o1 = (a1 * cs - a2 * sn) * qsc;
        const float o2 = (a2 * cs + a1 * sn) * qsc;
        if (sel == 0) {
            row[h * HD + d1] = (half_t)o1;
            row[h * HD + d2] = (half_t)o2;
        } else {
            half_t* kdst = Kf + (((size_t)(b * HH + h) * 36 + g36) * 2 + jt) * 2048
                         + ktile * 1024;
            kdst[(size_t)(d1 >> 5) * 512 + (km + 16 * ((d1 & 31) >> 3)) * 8 + (d1 & 7)]
                = (half_t)o1;
            kdst[(size_t)(d2 >> 5) * 512 + (km + 16 * ((d2 & 31) >> 3)) * 8 + (d2 & 7)]
                = (half_t)o2;
        }
    }
}

// ---------------------------------------------------------------------------
// Flash attention v7: 32-j softmax frames, all-K=32 MFMA, register-direct
// K/V (zero main-loop barriers). Wave w owns (jt=w&1, qh=w>>1); per step g
// it processes its 32 j's of the 64-token group: 4 QK^T MFMAs + ONE softmax
// update + 4 PV MFMAs (scA∪scB concatenate into the K=32 PV B-operand via
// the Kf permutation). Distance-1 register prefetch; LDS only for the
// 2-way epilogue merge.
// ---------------------------------------------------------------------------
__global__ __launch_bounds__(256, 4)
void flash_attn_mfma7(const half_t* __restrict__ qkvh, const half_t* __restrict__ Kf,
                      const half_t* __restrict__ Vf, half_t* __restrict__ attn_h)
{
    const int flat = blockIdx.x;         // 0..1151, XCD-swizzled
    const int xcd  = flat & 7;
    const int jj   = flat >> 3;          // 0..143
    const int bh   = xcd * 4 + (jj / 36);
    const int qtb  = jj % 36;
    const int b    = bh >> 4, h = bh & 15;
    const int t    = threadIdx.x;
    const int w    = t >> 6;
    const int jt   = w & 1;              // wave's j-slice within each group
    const int qh   = w >> 1;             // wave's q-half (32 q rows)
    const int lane = t & 63;
    const int l15  = lane & 15, quad = lane >> 4;

    const size_t tb = (size_t)b * SS;
    const int q0 = qtb * 64;

    __shared__ float mlb[4][32][2];      // per-wave (m, l) for its 32 q's
    __shared__ float Ob[2][64][33];      // [qh][d][q], padded stride 33

    // Q B-frags (loop invariant): B[k=quad*8+i][n=l15], 2 q-tiles of this q-half
    half8 qf[2][2];
    #pragma unroll
    for (int qt = 0; qt < 2; ++qt)
        #pragma unroll
        for (int dt2 = 0; dt2 < 2; ++dt2)
            qf[qt][dt2] = *(const half8*)(qkvh + (tb + q0 + qh * 32 + qt * 16 + l15) * 3072
                                          + h * HD + dt2 * 32 + quad * 8);

    f32x4 acc[4][2];                     // [dt][qt] : O^T[dt*16+quad*4+reg][q]
    float m_i[2], l_i[2];
    #pragma unroll
    for (int qt = 0; qt < 2; ++qt) {
        m_i[qt] = -INFINITY; l_i[qt] = 0.f;
        #pragma unroll
        for (int dt = 0; dt < 4; ++dt) acc[dt][qt] = (f32x4){0.f, 0.f, 0.f, 0.f};
    }

    // wave's per-step load pointers; step stride = 4096 halfs (2 jt slots)
    const half_t* kpl = Kf + (((size_t)bh * 36) * 2 + jt) * 2048 + lane * 8;
    const half_t* vpl = Vf + (((size_t)bh * 36) * 2 + jt) * 2048 + lane * 8;

    // one step: 32 j's -> QK^T, one softmax frame, K=32 PV
    auto step = [&](half8 kA0, half8 kA1, half8 kB0, half8 kB1,
                    half8 v0, half8 v1, half8 v2, half8 v3) {
        f32x4 scA[2], scB[2];
        #pragma unroll
        for (int qt = 0; qt < 2; ++qt) {
            scA[qt] = (f32x4){0.f, 0.f, 0.f, 0.f};
            scB[qt] = (f32x4){0.f, 0.f, 0.f, 0.f};
            scA[qt] = __builtin_amdgcn_mfma_f32_16x16x32_f16(kA0, qf[qt][0], scA[qt], 0, 0, 0);
            scA[qt] = __builtin_amdgcn_mfma_f32_16x16x32_f16(kA1, qf[qt][1], scA[qt], 0, 0, 0);
            scB[qt] = __builtin_amdgcn_mfma_f32_16x16x32_f16(kB0, qf[qt][0], scB[qt], 0, 0, 0);
            scB[qt] = __builtin_amdgcn_mfma_f32_16x16x32_f16(kB1, qf[qt][1], scB[qt], 0, 0, 0);
        }
        half8 pf[2];
        #pragma unroll
        for (int qt = 0; qt < 2; ++qt) {
            float mx = fmaxf(fmaxf(fmaxf(scA[qt][0], scA[qt][1]),
                                   fmaxf(scA[qt][2], scA[qt][3])),
                             fmaxf(fmaxf(scB[qt][0], scB[qt][1]),
                                   fmaxf(scB[qt][2], scB[qt][3])));
            mx = fmaxf(mx, __shfl_xor(mx, 16));
            mx = fmaxf(mx, __shfl_xor(mx, 32));
            if (__any(mx > m_i[qt])) {
                const float mn = fmaxf(m_i[qt], mx);
                const float alpha = EXP2(m_i[qt] - mn);
                m_i[qt] = mn;
                l_i[qt] *= alpha;
                #pragma unroll
                for (int dt = 0; dt < 4; ++dt) acc[dt][qt] *= alpha;
            }
            const float m = m_i[qt];
            const float pA0 = EXP2(scA[qt][0] - m);
            const float pA1 = EXP2(scA[qt][1] - m);
            const float pA2 = EXP2(scA[qt][2] - m);
            const float pA3 = EXP2(scA[qt][3] - m);
            const float pB0 = EXP2(scB[qt][0] - m);
            const float pB1 = EXP2(scB[qt][1] - m);
            const float pB2 = EXP2(scB[qt][2] - m);
            const float pB3 = EXP2(scB[qt][3] - m);
            l_i[qt] += ((pA0 + pA1) + (pA2 + pA3)) + ((pB0 + pB1) + (pB2 + pB3));
            pf[qt] = (half8){(half_t)pA0, (half_t)pA1, (half_t)pA2, (half_t)pA3,
                             (half_t)pB0, (half_t)pB1, (half_t)pB2, (half_t)pB3};
        }
        half8 vf[4] = {v0, v1, v2, v3};
        #pragma unroll
        for (int dt = 0; dt < 4; ++dt)
            #pragma unroll
            for (int qt = 0; qt < 2; ++qt)
                acc[dt][qt] = __builtin_amdgcn_mfma_f32_16x16x32_f16(
                    vf[dt], pf[qt], acc[dt][qt], 0, 0, 0);
    };

    // software pipeline: register double-buffer, distance-1 prefetch
    half8 kA0 = *(const half8*)(kpl);
    half8 kA1 = *(const half8*)(kpl + 512);
    half8 kB0 = *(const half8*)(kpl + 1024);
    half8 kB1 = *(const half8*)(kpl + 1536);
    half8 va0 = *(const half8*)(vpl);
    half8 va1 = *(const half8*)(vpl + 512);
    half8 va2 = *(const half8*)(vpl + 1024);
    half8 va3 = *(const half8*)(vpl + 1536);

    for (int g2 = 0; g2 < 18; ++g2) {
        const int g = g2 * 2;
        // prefetch step g+1 (always exists: g <= 34)
        const half_t* kN = kpl + (size_t)(g + 1) * 4096;
        const half_t* vN = vpl + (size_t)(g + 1) * 4096;
        half8 nk0 = *(const half8*)(kN);
        half8 nk1 = *(const half8*)(kN + 512);
        half8 nk2 = *(const half8*)(kN + 1024);
        half8 nk3 = *(const half8*)(kN + 1536);
        half8 nv0 = *(const half8*)(vN);
        half8 nv1 = *(const half8*)(vN + 512);
        half8 nv2 = *(const half8*)(vN + 1024);
        half8 nv3 = *(const half8*)(vN + 1536);

        step(kA0, kA1, kB0, kB1, va0, va1, va2, va3);

        if (g + 2 < 36) {                // prefetch step g+2
            const half_t* kM = kpl + (size_t)(g + 2) * 4096;
            const half_t* vM = vpl + (size_t)(g + 2) * 4096;
            kA0 = *(const half8*)(kM);
            kA1 = *(const half8*)(kM + 512);
            kB0 = *(const half8*)(kM + 1024);
            kB1 = *(const half8*)(kM + 1536);
            va0 = *(const half8*)(vM);
            va1 = *(const half8*)(vM + 512);
            va2 = *(const half8*)(vM + 1024);
            va3 = *(const half8*)(vM + 1536);
        }

        step(nk0, nk1, nk2, nk3, nv0, nv1, nv2, nv3);
    }

    // ---- 2-way merge: waves (jt=0, jt=1) of the same q-half ----
    #pragma unroll
    for (int qt = 0; qt < 2; ++qt) {      // cross-quad reduce lane-local l
        float lq = l_i[qt];
        lq += __shfl_xor(lq, 16);
        lq += __shfl_xor(lq, 32);
        if (quad == 0) {
            mlb[w][qt * 16 + l15][0] = m_i[qt];
            mlb[w][qt * 16 + l15][1] = lq;
        }
    }
    __syncthreads();

    float fac[2];
    #pragma unroll
    for (int qt = 0; qt < 2; ++qt) {
        const int q = qt * 16 + l15;
        const float m0 = mlb[qh * 2 + 0][q][0], m1 = mlb[qh * 2 + 1][q][0];
        const float M  = fmaxf(m0, m1);
        const float L  = mlb[qh * 2 + 0][q][1] * EXP2(m0 - M)
                       + mlb[qh * 2 + 1][q][1] * EXP2(m1 - M);
        fac[qt] = EXP2(m_i[qt] - M) / L;
    }

    #pragma unroll
    for (int ph = 0; ph < 2; ++ph) {
        if (jt == ph) {
            #pragma unroll
            for (int dt = 0; dt < 4; ++dt)
                #pragma unroll
                for (int qt = 0; qt < 2; ++qt)
                    #pragma unroll
                    for (int rg = 0; rg < 4; ++rg) {
                        const int d = dt * 16 + quad * 4 + rg;
                        const int q = qt * 16 + l15;
                        const float v = acc[dt][qt][rg] * fac[qt];
                        if (ph == 0) Ob[qh][d][q] = v;
                        else         Ob[qh][d][q] += v;
                    }
        }
        __syncthreads();
    }

    // ---- store O as f16, tile-blocked [mb][kb][128][32] for the proj GEMM ----
    {
        const int q   = t >> 2;              // token within q-tile (0..63)
        const int ds  = (t & 3) * 16;
        const int qh2 = q >> 5, qq = q & 31;
        const size_t mrow = tb + q0 + q;
        const int mb2 = (int)(mrow >> 7);
        const int mm  = (int)(mrow & 127);
        #pragma unroll
        for (int g = 0; g < 4; ++g) {
            const int dd = ds + 4 * g;
            const int kb2 = (h * HD + dd) >> 5;
            const int kk  = dd & 31;
            half4 o;
            o[0] = (half_t)Ob[qh2][dd + 0][qq];
            o[1] = (half_t)Ob[qh2][dd + 1][qq];
            o[2] = (half_t)Ob[qh2][dd + 2][qq];
            o[3] = (half_t)Ob[qh2][dd + 3][qq];
            *(half4*)(attn_h + ((size_t)mb2 * 32 + kb2) * 4096 + mm * 32 + kk) = o;
        }
    }
}

// ---------------------------------------------------------------------------
// Launch
// ---------------------------------------------------------------------------
extern "C" void kernel_launch(void* const* d_in, const int* in_sizes, int n_in,
                              void* d_out, int out_size, void* d_ws, size_t ws_size,
                              hipStream_t stream)
{
    const float* input   = (const float*)d_in[0];
    const float* qkv_w   = (const float*)d_in[1];
    const float* qkv_b   = (const float*)d_in[2];
    const float* q_scale = (const float*)d_in[3];
    const float* k_scale = (const float*)d_in[4];
    const float* proj_w  = (const float*)d_in[5];
    const float* proj_b  = (const float*)d_in[6];
    const int*   width   = (const int*)d_in[8];
    float* out = (float*)d_out;

    // ws layout (all f16): qkv_h 28.3MB | attn_h 9.4 | Vf 9.4 | Ah 9.4 (reused
    // as Kf after GEMM1) | Bh1 6.3 | Bh2 2.1  => 65.0 MB total
    half_t* qkvh   = (half_t*)d_ws;
    half_t* attn_h = qkvh   + (size_t)4608 * 3072;
    half_t* Vf     = attn_h + (size_t)4608 * 1024;
    half_t* Ah     = Vf     + (size_t)32 * 36 * 2 * 2048;
    half_t* Bh1    = Ah     + (size_t)4608 * 1024;
    half_t* Bh2    = Bh1    + (size_t)3072 * 1024;
    half_t* Kf     = Ah;    // Ah is dead after GEMM1; Kf is written by normrope

    const int M = BB * SS;   // 4608

    // 0) fp32 -> f16 tile-blocked converters (proj_w 64-row-blocked)
    convert_tile_f16<128><<<dim3(M / 128, DINC / 32),        256, 0, stream>>>(input,  Ah,  DINC);
    convert_tile_f16<128><<<dim3(3 * DIMC / 128, DINC / 32), 256, 0, stream>>>(qkv_w, Bh1, DINC);
    convert_tile_f16<64><<<dim3(DINC / 64, DIMC / 32),       256, 0, stream>>>(proj_w, Bh2, DIMC);

    // 1) qkv_h = f16( input @ qkv_w^T + qkv_b )
    gemm_mfma<128, true><<<dim3(3 * DIMC / 128, M / 128), 256, 0, stream>>>(
        Ah, Bh1, qkv_b, qkvh, M, 3 * DIMC, DINC);

    // 2) RMSNorm + RoPE: Q in place (log2-scaled), K -> Kf, V -> Vf
    normrope_v7<<<M, 512, 0, stream>>>(qkvh, q_scale, k_scale, width, Kf, Vf);

    // 3) MFMA flash attention -> attn_h (f16, tile-blocked), XCD-swizzled
    flash_attn_mfma7<<<dim3(SS / 64 * BB * HH), 256, 0, stream>>>(qkvh, Kf, Vf, attn_h);

    // 4) out = attn @ proj_w^T + proj_b  (fp32 out, BN=64 for occupancy)
    gemm_mfma<64, false><<<dim3(DINC / 64, M / 128), 256, 0, stream>>>(
        attn_h, Bh2, proj_b, out, M, DINC, DIMC);
}

// Round 10
// 266.035 us; speedup vs baseline: 1.2215x; 1.2215x over previous
//
#include <hip/hip_runtime.h>
#include <math.h>

// Problem constants (fixed by the reference)
#define BB   2
#define SS   2304
#define DINC 1024
#define DIMC 1024
#define HH   16
#define HD   64

typedef _Float16 half_t;
typedef __attribute__((ext_vector_type(4))) _Float16 half4;   // 2 VGPRs
typedef __attribute__((ext_vector_type(8))) _Float16 half8;   // 4 VGPRs
typedef __attribute__((ext_vector_type(4))) float    f32x4;   // 4 VGPRs

#define LOG2E 1.44269504088896340736f
#define EXP2(x) __builtin_amdgcn_exp2f(x)     // raw v_exp_f32, no libm guard path

__device__ __forceinline__ half4 lo4(half8 x) { return (half4){x[0], x[1], x[2], x[3]}; }
__device__ __forceinline__ half4 hi4(half8 x) { return (half4){x[4], x[5], x[6], x[7]}; }

// async global->LDS, 16B per lane; LDS dest = wave-uniform base + lane*16
#define GLOAD_LDS16(gp, lp)                                                     \
    __builtin_amdgcn_global_load_lds(                                           \
        (const __attribute__((address_space(1))) void*)(gp),                    \
        (__attribute__((address_space(3))) void*)(lp), 16, 0, 0)

// ---------------------------------------------------------------------------
// Converter: fp32 row-major [R][K] -> f16 tile-blocked [R/RB][K/32][RB][32].
// ---------------------------------------------------------------------------
template<int RB>
__global__ __launch_bounds__(256)
void convert_tile_f16(const float* __restrict__ src, half_t* __restrict__ dst, int K)
{
    constexpr int EPT = RB * 32 / 256;       // elements per thread (16 or 8)
    const int mb = blockIdx.x;
    const int kb = blockIdx.y;
    const int t  = threadIdx.x;
    const int e0 = t * EPT;
    const int mm = e0 >> 5;
    const int kk = e0 & 31;
    const float* sp = src + (size_t)(mb * RB + mm) * K + kb * 32 + kk;
    half_t*      dp = dst + ((size_t)mb * (K >> 5) + kb) * (RB * 32) + mm * 32 + kk;
    #pragma unroll
    for (int g = 0; g < EPT / 4; ++g) {
        float4 v = *(const float4*)(sp + 4 * g);
        dp[4 * g + 0] = (half_t)v.x; dp[4 * g + 1] = (half_t)v.y;
        dp[4 * g + 2] = (half_t)v.z; dp[4 * g + 3] = (half_t)v.w;
    }
}

// ---------------------------------------------------------------------------
// f16 MFMA GEMM (NT): C[m][n] = sum_k A[m][k]*W[n][k] + bias[n], fp32 accum.
// (unchanged from round 8)
// ---------------------------------------------------------------------------
template<int BN, bool OUT_HALF>
__global__ __launch_bounds__(256)
void gemm_mfma(const half_t* __restrict__ Ah, const half_t* __restrict__ Bh,
               const float* __restrict__ bias, void* __restrict__ Cout,
               int M, int N, int K)
{
    constexpr int MT = (BN == 128) ? 4 : 2;
    constexpr int NT = 4;
    const int KB = K >> 5;
    __shared__ half_t As[8192];          // [u][128][32]
    __shared__ half_t Bs[2 * BN * 32];   // [u][BN][32]

    const int t    = threadIdx.x;
    const int w    = t >> 6;
    const int lane = t & 63;
    const int l15  = lane & 15, quad = lane >> 4;
    const int wr   = (BN == 128) ? (w >> 1) : w;
    const int wc   = (BN == 128) ? (w & 1) : 0;
    const int mb   = blockIdx.y, nb = blockIdx.x;

    f32x4 acc[MT][NT];
    #pragma unroll
    for (int mt = 0; mt < MT; ++mt)
        #pragma unroll
        for (int nt = 0; nt < NT; ++nt) acc[mt][nt] = (f32x4){0.f, 0.f, 0.f, 0.f};

    const half_t* atile = Ah + (size_t)mb * KB * 4096;
    const half_t* btile = Bh + (size_t)nb * KB * (BN * 32);

    for (int kb = 0; kb < KB; kb += 2) {
        #pragma unroll
        for (int u = 0; u < 2; ++u) {
            const half_t* at = atile + (size_t)(kb + u) * 4096;
            const half_t* bt = btile + (size_t)(kb + u) * (BN * 32);
            #pragma unroll
            for (int v = 0; v < 2; ++v) {
                const int ch = w * 2 + v;
                GLOAD_LDS16(at + ch * 512 + lane * 8, As + u * 4096 + ch * 512);
            }
            if (BN == 128) {
                #pragma unroll
                for (int v = 0; v < 2; ++v) {
                    const int ch = w * 2 + v;
                    GLOAD_LDS16(bt + ch * 512 + lane * 8, Bs + u * 4096 + ch * 512);
                }
            } else {
                GLOAD_LDS16(bt + w * 512 + lane * 8, Bs + u * (BN * 32) + w * 512);
            }
        }
        __syncthreads();

        #pragma unroll
        for (int u = 0; u < 2; ++u) {
            half8 af[MT], bf[NT];
            #pragma unroll
            for (int mt = 0; mt < MT; ++mt)
                af[mt] = *(const half8*)(As + u * 4096
                                         + (wr * (MT * 16) + mt * 16 + l15) * 32 + quad * 8);
            #pragma unroll
            for (int nt = 0; nt < NT; ++nt)
                bf[nt] = *(const half8*)(Bs + u * (BN * 32)
                                         + (wc * 64 + nt * 16 + l15) * 32 + quad * 8);
            #pragma unroll
            for (int mt = 0; mt < MT; ++mt)
                #pragma unroll
                for (int nt = 0; nt < NT; ++nt)
                    acc[mt][nt] = __builtin_amdgcn_mfma_f32_16x16x32_f16(
                        af[mt], bf[nt], acc[mt][nt], 0, 0, 0);
        }
        __syncthreads();
    }

    const int bm = mb * 128, bn = nb * BN;
    #pragma unroll
    for (int nt = 0; nt < NT; ++nt) {
        const int n  = bn + wc * 64 + nt * 16 + l15;
        const float bv = bias[n];
        #pragma unroll
        for (int mt = 0; mt < MT; ++mt) {
            const int m0 = bm + wr * (MT * 16) + mt * 16 + quad * 4;
            #pragma unroll
            for (int rg = 0; rg < 4; ++rg) {
                const float v = acc[mt][nt][rg] + bv;
                if (OUT_HALF) ((half_t*)Cout)[(size_t)(m0 + rg) * N + n] = (half_t)v;
                else          ((float*) Cout)[(size_t)(m0 + rg) * N + n] = v;
            }
        }
    }
}

// ---------------------------------------------------------------------------
// RMSNorm (full 1024) + axial 2D RoPE on the f16 qkv buffer (fp32 math).
// (round-8 version, unchanged; Kf/Vf fragment-stream layouts per comments)
// ---------------------------------------------------------------------------
__global__ __launch_bounds__(256)
void normrope_v6(half_t* __restrict__ qkvh, const float* __restrict__ q_scale,
                 const float* __restrict__ k_scale, const int* __restrict__ wptr,
                 half_t* __restrict__ Kf, half_t* __restrict__ Vf)
{
    const int token = blockIdx.x;        // b*SS + s
    const int s     = token % SS;
    const int b     = token / SS;
    const int w     = *wptr;
    const int t     = threadIdx.x;
    const float rowp = (float)(s / w);
    const float colp = (float)(s % w);

    half_t* base = qkvh + (size_t)token * 3072;

    const int fr = s >> 5;
    const int jt = (s >> 4) & 1;

    // ---- V -> Vf ----
    {
        half4 v4 = *(const half4*)(base + 2048 + 4 * t);
        const int dabs0 = 4 * t;
        const int h  = dabs0 >> 6;
        const int vq = (s & 15) >> 2;
        const int vi = s & 3;
        half_t* vdst = Vf + ((size_t)(b * HH + h) * 72 + fr) * 2048 + jt * 1024;
        #pragma unroll
        for (int ii = 0; ii < 4; ++ii) {
            const int d   = (dabs0 + ii) & 63;
            const int dt  = d >> 4;
            vdst[(size_t)(dt >> 1) * 512 + ((d & 15) + 16 * vq) * 8 + (dt & 1) * 4 + vi]
                = v4[ii];
        }
    }

    __shared__ float buf[DIMC];
    __shared__ float red[4];

    const int km = s & 15;               // token's row within its j-tile

    #pragma unroll
    for (int sel = 0; sel < 2; ++sel) {
        half_t* row = base + sel * DIMC;
        const float* scp = sel ? k_scale : q_scale;

        half4 xh = *(const half4*)(row + 4 * t);
        float x0 = (float)xh[0], x1 = (float)xh[1], x2 = (float)xh[2], x3 = (float)xh[3];
        float ss = x0 * x0 + x1 * x1 + x2 * x2 + x3 * x3;
        #pragma unroll
        for (int o = 32; o >= 1; o >>= 1) ss += __shfl_xor(ss, o);
        if ((t & 63) == 0) red[t >> 6] = ss;
        __syncthreads();

        const float rinv = rsqrtf((red[0] + red[1] + red[2] + red[3]) * (1.0f / DIMC) + 1e-6f);
        float4 g = *(const float4*)(scp + 4 * t);
        buf[4 * t + 0] = x0 * rinv * g.x;
        buf[4 * t + 1] = x1 * rinv * g.y;
        buf[4 * t + 2] = x2 * rinv * g.z;
        buf[4 * t + 3] = x3 * rinv * g.w;
        __syncthreads();

        const float qsc = sel ? 1.0f : (0.125f * LOG2E);  // log2-domain scores

        #pragma unroll
        for (int pp = 0; pp < 2; ++pp) {
            const int p = t + pp * 256;
            const int h = p >> 5;
            const int r = p & 31;
            const int j = r & 15;
            const float pos = (r < 16) ? rowp : colp;
            const int d1 = (r < 16) ? j : (32 + j);   // within-head dim
            const int d2 = d1 + 16;
            const float freq = exp2f((float)j * -0.83048202372f);
            const float ang  = pos * freq;
            float sn, cs;
            __sincosf(ang, &sn, &cs);
            const float a1 = buf[h * HD + d1], a2 = buf[h * HD + d2];
            const float o1 = (a1 * cs - a2 * sn) * qsc;
            const float o2 = (a2 * cs + a1 * sn) * qsc;
            if (sel == 0) {
                row[h * HD + d1] = (half_t)o1;
                row[h * HD + d2] = (half_t)o2;
            } else {
                half_t* kdst = Kf + ((size_t)(b * HH + h) * 72 + fr) * 2048 + jt * 1024;
                kdst[(size_t)(d1 >> 5) * 512 + (km + 16 * ((d1 & 31) >> 3)) * 8 + (d1 & 7)]
                    = (half_t)o1;
                kdst[(size_t)(d2 >> 5) * 512 + (km + 16 * ((d2 & 31) >> 3)) * 8 + (d2 & 7)]
                    = (half_t)o2;
            }
        }
        __syncthreads();   // buf/red reused by next sel
    }
}

// ---------------------------------------------------------------------------
// Flash attention v8: round-8 structure (register-direct K/V, zero main-loop
// barriers, 16-j frame loads) + PAIRED-FRAME softmax: one online-softmax
// update per 2 frames (32 j) over the combined 8 scores/lane. Register
// discipline: next-pair K loads issue after QK^T (kA/kB dead), next-pair V
// loads after PV (vA/vB dead) -> peak buffer liveness = 32 VGPRs, same as
// round 8 (no spill; round 9's 64-reg buffering spilled to scratch).
// ---------------------------------------------------------------------------
__global__ __launch_bounds__(256, 4)
void flash_attn_mfma8(const half_t* __restrict__ qkvh, const half_t* __restrict__ Kf,
                      const half_t* __restrict__ Vf, half_t* __restrict__ attn_h)
{
    const int flat = blockIdx.x;         // 0..1151, XCD-swizzled
    const int xcd  = flat & 7;
    const int jj   = flat >> 3;          // 0..143
    const int bh   = xcd * 4 + (jj / 36);
    const int qtb  = jj % 36;
    const int b    = bh >> 4, h = bh & 15;
    const int t    = threadIdx.x;
    const int w    = t >> 6;
    const int jt   = w & 1;              // wave's j-tile within each frame
    const int qh   = w >> 1;             // wave's q-half (32 q rows)
    const int lane = t & 63;
    const int l15  = lane & 15, quad = lane >> 4;

    const size_t tb = (size_t)b * SS;
    const int q0 = qtb * 64;

    __shared__ float mlb[4][32][2];      // per-wave (m, l) for its 32 q's
    __shared__ float Ob[2][64][33];      // [qh][d][q], padded stride 33

    // Q B-frags (loop invariant): B[k=quad*8+i][n=l15], 2 q-tiles of this q-half
    half8 qf[2][2];
    #pragma unroll
    for (int qt = 0; qt < 2; ++qt)
        #pragma unroll
        for (int dt2 = 0; dt2 < 2; ++dt2)
            qf[qt][dt2] = *(const half8*)(qkvh + (tb + q0 + qh * 32 + qt * 16 + l15) * 3072
                                          + h * HD + dt2 * 32 + quad * 8);

    f32x4 acc[4][2];                     // [dt][qt] : O^T[dt*16+quad*4+reg][q]
    float m_i[2], l_i[2];
    #pragma unroll
    for (int qt = 0; qt < 2; ++qt) {
        m_i[qt] = -INFINITY; l_i[qt] = 0.f;
        #pragma unroll
        for (int dt = 0; dt < 4; ++dt) acc[dt][qt] = (f32x4){0.f, 0.f, 0.f, 0.f};
    }

    // wave's per-frame load pointers (frames stride 2048 halfs)
    const half_t* kpl = Kf + (size_t)bh * 72 * 2048 + jt * 1024 + lane * 8;
    const half_t* vpl = Vf + (size_t)bh * 72 * 2048 + jt * 1024 + lane * 8;

    // initial pair (frames 0,1)
    half8 kA0 = *(const half8*)(kpl);
    half8 kA1 = *(const half8*)(kpl + 512);
    half8 kB0 = *(const half8*)(kpl + 2048);
    half8 kB1 = *(const half8*)(kpl + 2560);
    half8 vA0 = *(const half8*)(vpl);
    half8 vA1 = *(const half8*)(vpl + 512);
    half8 vB0 = *(const half8*)(vpl + 2048);
    half8 vB1 = *(const half8*)(vpl + 2560);

    for (int p = 0; p < 36; ++p) {
        // ---- S^T for both frames (kA/kB dead afterwards) ----
        f32x4 scA[2], scB[2];
        #pragma unroll
        for (int qt = 0; qt < 2; ++qt) {
            scA[qt] = (f32x4){0.f, 0.f, 0.f, 0.f};
            scA[qt] = __builtin_amdgcn_mfma_f32_16x16x32_f16(kA0, qf[qt][0], scA[qt], 0, 0, 0);
            scA[qt] = __builtin_amdgcn_mfma_f32_16x16x32_f16(kA1, qf[qt][1], scA[qt], 0, 0, 0);
            scB[qt] = (f32x4){0.f, 0.f, 0.f, 0.f};
            scB[qt] = __builtin_amdgcn_mfma_f32_16x16x32_f16(kB0, qf[qt][0], scB[qt], 0, 0, 0);
            scB[qt] = __builtin_amdgcn_mfma_f32_16x16x32_f16(kB1, qf[qt][1], scB[qt], 0, 0, 0);
        }

        // ---- prefetch next pair's K into the now-dead kA/kB registers ----
        if (p + 1 < 36) {
            const half_t* kN = kpl + (size_t)(p + 1) * 4096;
            kA0 = *(const half8*)(kN);
            kA1 = *(const half8*)(kN + 512);
            kB0 = *(const half8*)(kN + 2048);
            kB1 = *(const half8*)(kN + 2560);
        }

        // ---- ONE softmax update over both frames (8 scores/lane per qt) ----
        half4 pfA[2], pfB[2];
        #pragma unroll
        for (int qt = 0; qt < 2; ++qt) {
            float mx = fmaxf(fmaxf(fmaxf(scA[qt][0], scA[qt][1]),
                                   fmaxf(scA[qt][2], scA[qt][3])),
                             fmaxf(fmaxf(scB[qt][0], scB[qt][1]),
                                   fmaxf(scB[qt][2], scB[qt][3])));
            mx = fmaxf(mx, __shfl_xor(mx, 16));
            mx = fmaxf(mx, __shfl_xor(mx, 32));
            if (__any(mx > m_i[qt])) {
                const float mn = fmaxf(m_i[qt], mx);
                const float alpha = EXP2(m_i[qt] - mn);
                m_i[qt] = mn;
                l_i[qt] *= alpha;
                #pragma unroll
                for (int dt = 0; dt < 4; ++dt) acc[dt][qt] *= alpha;
            }
            const float m = m_i[qt];
            const float a0 = EXP2(scA[qt][0] - m);
            const float a1 = EXP2(scA[qt][1] - m);
            const float a2 = EXP2(scA[qt][2] - m);
            const float a3 = EXP2(scA[qt][3] - m);
            const float b0 = EXP2(scB[qt][0] - m);
            const float b1 = EXP2(scB[qt][1] - m);
            const float b2 = EXP2(scB[qt][2] - m);
            const float b3 = EXP2(scB[qt][3] - m);
            l_i[qt] += ((a0 + a1) + (a2 + a3)) + ((b0 + b1) + (b2 + b3));
            pfA[qt] = (half4){(half_t)a0, (half_t)a1, (half_t)a2, (half_t)a3};
            pfB[qt] = (half4){(half_t)b0, (half_t)b1, (half_t)b2, (half_t)b3};
        }

        // ---- O^T += V^T . P^T for both frames (vA/vB dead afterwards) ----
        half4 vfA[4] = {lo4(vA0), hi4(vA0), lo4(vA1), hi4(vA1)};
        half4 vfB[4] = {lo4(vB0), hi4(vB0), lo4(vB1), hi4(vB1)};
        #pragma unroll
        for (int dt = 0; dt < 4; ++dt)
            #pragma unroll
            for (int qt = 0; qt < 2; ++qt) {
                acc[dt][qt] = __builtin_amdgcn_mfma_f32_16x16x16f16(
                    vfA[dt], pfA[qt], acc[dt][qt], 0, 0, 0);
                acc[dt][qt] = __builtin_amdgcn_mfma_f32_16x16x16f16(
                    vfB[dt], pfB[qt], acc[dt][qt], 0, 0, 0);
            }

        // ---- prefetch next pair's V into the now-dead vA/vB registers ----
        if (p + 1 < 36) {
            const half_t* vN = vpl + (size_t)(p + 1) * 4096;
            vA0 = *(const half8*)(vN);
            vA1 = *(const half8*)(vN + 512);
            vB0 = *(const half8*)(vN + 2048);
            vB1 = *(const half8*)(vN + 2560);
        }
    }

    // ---- 2-way merge: waves (jt=0, jt=1) of the same q-half ----
    #pragma unroll
    for (int qt = 0; qt < 2; ++qt) {      // cross-quad reduce lane-local l
        float lq = l_i[qt];
        lq += __shfl_xor(lq, 16);
        lq += __shfl_xor(lq, 32);
        if (quad == 0) {
            mlb[w][qt * 16 + l15][0] = m_i[qt];
            mlb[w][qt * 16 + l15][1] = lq;
        }
    }
    __syncthreads();

    float fac[2];
    #pragma unroll
    for (int qt = 0; qt < 2; ++qt) {
        const int q = qt * 16 + l15;
        const float m0 = mlb[qh * 2 + 0][q][0], m1 = mlb[qh * 2 + 1][q][0];
        const float M  = fmaxf(m0, m1);
        const float L  = mlb[qh * 2 + 0][q][1] * EXP2(m0 - M)
                       + mlb[qh * 2 + 1][q][1] * EXP2(m1 - M);
        fac[qt] = EXP2(m_i[qt] - M) / L;
    }

    #pragma unroll
    for (int ph = 0; ph < 2; ++ph) {
        if (jt == ph) {
            #pragma unroll
            for (int dt = 0; dt < 4; ++dt)
                #pragma unroll
                for (int qt = 0; qt < 2; ++qt)
                    #pragma unroll
                    for (int rg = 0; rg < 4; ++rg) {
                        const int d = dt * 16 + quad * 4 + rg;
                        const int q = qt * 16 + l15;
                        const float v = acc[dt][qt][rg] * fac[qt];
                        if (ph == 0) Ob[qh][d][q] = v;
                        else         Ob[qh][d][q] += v;
                    }
        }
        __syncthreads();
    }

    // ---- store O as f16, tile-blocked [mb][kb][128][32] for the proj GEMM ----
    {
        const int q   = t >> 2;              // token within q-tile (0..63)
        const int ds  = (t & 3) * 16;
        const int qh2 = q >> 5, qq = q & 31;
        const size_t mrow = tb + q0 + q;
        const int mb2 = (int)(mrow >> 7);
        const int mm  = (int)(mrow & 127);
        #pragma unroll
        for (int g = 0; g < 4; ++g) {
            const int dd = ds + 4 * g;
            const int kb2 = (h * HD + dd) >> 5;
            const int kk  = dd & 31;
            half4 o;
            o[0] = (half_t)Ob[qh2][dd + 0][qq];
            o[1] = (half_t)Ob[qh2][dd + 1][qq];
            o[2] = (half_t)Ob[qh2][dd + 2][qq];
            o[3] = (half_t)Ob[qh2][dd + 3][qq];
            *(half4*)(attn_h + ((size_t)mb2 * 32 + kb2) * 4096 + mm * 32 + kk) = o;
        }
    }
}

// ---------------------------------------------------------------------------
// Launch
// ---------------------------------------------------------------------------
extern "C" void kernel_launch(void* const* d_in, const int* in_sizes, int n_in,
                              void* d_out, int out_size, void* d_ws, size_t ws_size,
                              hipStream_t stream)
{
    const float* input   = (const float*)d_in[0];
    const float* qkv_w   = (const float*)d_in[1];
    const float* qkv_b   = (const float*)d_in[2];
    const float* q_scale = (const float*)d_in[3];
    const float* k_scale = (const float*)d_in[4];
    const float* proj_w  = (const float*)d_in[5];
    const float* proj_b  = (const float*)d_in[6];
    const int*   width   = (const int*)d_in[8];
    float* out = (float*)d_out;

    // ws layout (all f16): qkv_h 28.3MB | attn_h 9.4 | Vf 9.4 | Ah 9.4 (reused
    // as Kf after GEMM1) | Bh1 6.3 | Bh2 2.1  => 65.0 MB total
    half_t* qkvh   = (half_t*)d_ws;
    half_t* attn_h = qkvh   + (size_t)4608 * 3072;
    half_t* Vf     = attn_h + (size_t)4608 * 1024;
    half_t* Ah     = Vf     + (size_t)32 * 72 * 2048;
    half_t* Bh1    = Ah     + (size_t)4608 * 1024;
    half_t* Bh2    = Bh1    + (size_t)3072 * 1024;
    half_t* Kf     = Ah;    // Ah is dead after GEMM1; Kf is written by normrope

    const int M = BB * SS;   // 4608

    // 0) fp32 -> f16 tile-blocked converters (proj_w 64-row-blocked)
    convert_tile_f16<128><<<dim3(M / 128, DINC / 32),        256, 0, stream>>>(input,  Ah,  DINC);
    convert_tile_f16<128><<<dim3(3 * DIMC / 128, DINC / 32), 256, 0, stream>>>(qkv_w, Bh1, DINC);
    convert_tile_f16<64><<<dim3(DINC / 64, DIMC / 32),       256, 0, stream>>>(proj_w, Bh2, DIMC);

    // 1) qkv_h = f16( input @ qkv_w^T + qkv_b )
    gemm_mfma<128, true><<<dim3(3 * DIMC / 128, M / 128), 256, 0, stream>>>(
        Ah, Bh1, qkv_b, qkvh, M, 3 * DIMC, DINC);

    // 2) RMSNorm + RoPE: Q in place (log2-scaled), K -> Kf, V -> Vf
    normrope_v6<<<M, 256, 0, stream>>>(qkvh, q_scale, k_scale, width, Kf, Vf);

    // 3) MFMA flash attention -> attn_h (f16, tile-blocked), XCD-swizzled
    flash_attn_mfma8<<<dim3(SS / 64 * BB * HH), 256, 0, stream>>>(qkvh, Kf, Vf, attn_h);

    // 4) out = attn @ proj_w^T + proj_b  (fp32 out, BN=64 for occupancy)
    gemm_mfma<64, false><<<dim3(DINC / 64, M / 128), 256, 0, stream>>>(
        attn_h, Bh2, proj_b, out, M, DINC, DIMC);
}